// Round 1
// baseline (260.903 us; speedup 1.0000x reference)
//
#include <hip/hip_runtime.h>

// AvgSeq: out[b,s,d] = (sum_{t<=s} x[b,t,d]) / (s+1)
// x: [16, 8192, 256] float32
//
// Three-pass chunked scan, float4-vectorized, deep load batching:
//   K1: chunk sums -> ws            (one wave per (b,chunk), lane = float4 col)
//   K2: exclusive scan of ws in-place (tiny, one wave per b)
//   K3: acc = ws[b,c] (single load) + serial scan of own chunk, 16-deep batches
#define BB 16
#define SS 8192
#define DD 256
#define D4 (DD / 4)     // 64 float4 columns; one wave covers all of D
#define NC 256          // chunks along S
#define CL (SS / NC)    // 32 steps per chunk
#define G  16           // register load-batch depth (16 KB in flight per wave)

__global__ __launch_bounds__(64) void avgseq_chunksum(const float4* __restrict__ x,
                                                      float4* __restrict__ ws) {
    const int blk = blockIdx.x;          // b*NC + c
    const int b = blk >> 8;              // / NC
    const int c = blk & (NC - 1);
    const int t = threadIdx.x;           // float4 column

    const float4* p = x + ((size_t)b * SS + (size_t)c * CL) * D4 + t;
    float4 acc = make_float4(0.f, 0.f, 0.f, 0.f);
    for (int s0 = 0; s0 < CL; s0 += G) {
        float4 v[G];
#pragma unroll
        for (int g = 0; g < G; ++g) v[g] = p[(size_t)(s0 + g) * D4];
#pragma unroll
        for (int g = 0; g < G; ++g) {
            acc.x += v[g].x; acc.y += v[g].y; acc.z += v[g].z; acc.w += v[g].w;
        }
    }
    ws[((size_t)b * NC + c) * D4 + t] = acc;
}

// In-place exclusive scan along chunks: ws[b,c,t] <- sum_{cc<c} ws[b,cc,t]
__global__ __launch_bounds__(64) void avgseq_scanws(float4* __restrict__ ws) {
    const int b = blockIdx.x;
    const int t = threadIdx.x;
    float4* w = ws + (size_t)b * NC * D4 + t;
    float4 run = make_float4(0.f, 0.f, 0.f, 0.f);
#pragma unroll 8
    for (int c = 0; c < NC; ++c) {
        float4 v = w[(size_t)c * D4];
        w[(size_t)c * D4] = run;
        run.x += v.x; run.y += v.y; run.z += v.z; run.w += v.w;
    }
}

__global__ __launch_bounds__(64) void avgseq_scan(const float4* __restrict__ x,
                                                  const float4* __restrict__ ws,
                                                  float4* __restrict__ out) {
    const int blk = blockIdx.x;          // b*NC + c
    const int b = blk >> 8;
    const int c = blk & (NC - 1);
    const int t = threadIdx.x;

    // exclusive prefix of preceding chunks: ONE load (ws already scanned)
    float4 acc = ws[((size_t)b * NC + c) * D4 + t];

    const size_t base = ((size_t)b * SS + (size_t)c * CL) * D4 + t;
    const float4* p = x + base;
    float4* o = out + base;
    const int s0 = c * CL;

    for (int ss = 0; ss < CL; ss += G) {
        float4 v[G];
#pragma unroll
        for (int g = 0; g < G; ++g) v[g] = p[(size_t)(ss + g) * D4];
        float4 ov[G];
#pragma unroll
        for (int g = 0; g < G; ++g) {
            acc.x += v[g].x; acc.y += v[g].y; acc.z += v[g].z; acc.w += v[g].w;
            const float r = __builtin_amdgcn_rcpf((float)(s0 + ss + g + 1));
            ov[g] = make_float4(acc.x * r, acc.y * r, acc.z * r, acc.w * r);
        }
#pragma unroll
        for (int g = 0; g < G; ++g) o[(size_t)(ss + g) * D4] = ov[g];
    }
}

extern "C" void kernel_launch(void* const* d_in, const int* in_sizes, int n_in,
                              void* d_out, int out_size, void* d_ws, size_t ws_size,
                              hipStream_t stream) {
    const float4* x = (const float4*)d_in[0];
    float4* out = (float4*)d_out;
    float4* ws = (float4*)d_ws;          // BB*NC*D4 float4 = 4 MiB

    const int nblocks = BB * NC;         // 4096 single-wave blocks = 16 waves/CU
    avgseq_chunksum<<<nblocks, 64, 0, stream>>>(x, ws);
    avgseq_scanws<<<BB, 64, 0, stream>>>(ws);
    avgseq_scan<<<nblocks, 64, 0, stream>>>(x, ws, out);
}